// Round 19
// baseline (345.074 us; speedup 1.0000x reference)
//
#include <hip/hip_runtime.h>
#include <hip/hip_cooperative_groups.h>
#include <hip/hip_bf16.h>

namespace cg = cooperative_groups;

#define BATCH 2
#define SEQ 2048
#define DM 512
#define NH 8
#define DHD 64
#define QP 256
#define KVP 341
#define DQKPAD 96
#define MROWS 4096   // BATCH*SEQ

// bf16 arena element offsets (x, W_o, LN params only)
#define OFF_X     0
#define OFF_WO    2932224
#define OFF_QG    3194368
#define OFF_QB    3194624
#define OFF_KG    3194880
#define OFF_KB    3195221

// transposed-weight arena element offsets ([N][K])
#define T_DQ   0
#define T_DKV  131072
#define T_KR   327680
#define T_UQ   360448
#define T_QR   491520
#define T_UKV  507904
#define T_TOT  901120

#define NW_PAR 1194

// prep work groups (8 elems each)
#define G_X   262144
#define G_WO  32768
#define G_PAR 150
#define G_WT  112640
#define G_TOT (G_X + G_WO + G_PAR + G_WT)
#define NPREPB ((G_TOT + 255) / 256)

#define NSPLIT 4
#define NBLK 256

typedef __bf16 bf16x8 __attribute__((ext_vector_type(8)));
typedef float f32x4 __attribute__((ext_vector_type(4)));
typedef __hip_bfloat16 bf16;
typedef unsigned short u16;

static __device__ __forceinline__ bf16x8 ld_bf8(const bf16* p) {
    return __builtin_bit_cast(bf16x8, *(const uint4*)p);
}

// async global->LDS, 16B per lane; LDS dest = wave-uniform base + lane*16
#define GL16(gp, lp) __builtin_amdgcn_global_load_lds( \
    (const __attribute__((address_space(1))) void*)(gp), \
    (__attribute__((address_space(3))) void*)(lp), 16, 0, 0)

// ---------- prep work item (8-wide) ----------
static __device__ __forceinline__ void prep_work(
    int gid, int f,
    const void* px, const void* pwdq, const void* pwuq, const void* pwqr,
    const void* pwdkv, const void* pwukv, const void* pwkr, const void* pwo,
    const void* pqg, const void* pqb, const void* pkg, const void* pkb,
    u16* __restrict__ arena, u16* __restrict__ WT)
{
    auto rdu = [&](const void* s, int i) -> u16 {
        if (f) return __builtin_bit_cast(u16, __float2bfloat16(((const float*)s)[i]));
        return ((const u16*)s)[i];
    };

    if (gid < G_X + G_WO) {
        const void* src = (gid < G_X) ? px : pwo;
        int base = (gid < G_X) ? OFF_X : OFF_WO;
        int i = (gid < G_X) ? gid : gid - G_X;
        u16 out[8];
        if (f) {
            const float* s = (const float*)src + i * 8;
            #pragma unroll
            for (int j = 0; j < 8; ++j) out[j] = __builtin_bit_cast(u16, __float2bfloat16(s[j]));
        } else {
            *(uint4*)out = ((const uint4*)src)[i];
        }
        *(uint4*)&arena[base + i * 8] = *(uint4*)out;
    } else if (gid < G_X + G_WO + G_PAR) {
        int i0 = (gid - G_X - G_WO) * 8;
        for (int j = 0; j < 8; ++j) {
            int i = i0 + j;
            if (i >= NW_PAR) break;
            if (i < 256)      arena[OFF_QG + i]         = rdu(pqg, i);
            else if (i < 512) arena[OFF_QB + (i - 256)] = rdu(pqb, i - 256);
            else if (i < 853) arena[OFF_KG + (i - 512)] = rdu(pkg, i - 512);
            else              arena[OFF_KB + (i - 853)] = rdu(pkb, i - 853);
        }
    } else {
        int loc = (gid - (G_X + G_WO + G_PAR)) * 8;
        const void* src; int n, k0, sN, klim, nok;
        if (loc < T_DKV)      { int l = loc;          n = l >> 9; k0 = l & 511; src = pwdq;  sN = 256;  klim = 512; nok = 1; }
        else if (loc < T_KR)  { int l = loc - T_DKV;  n = l >> 9; k0 = l & 511; src = pwdkv; sN = 341;  klim = 512; nok = (n < 341); }
        else if (loc < T_UQ)  { int l = loc - T_KR;   n = l >> 9; k0 = l & 511; src = pwkr;  sN = 64;   klim = 512; nok = 1; }
        else if (loc < T_QR)  { int l = loc - T_UQ;   n = l >> 8; k0 = l & 255; src = pwuq;  sN = 512;  klim = 256; nok = 1; }
        else if (loc < T_UKV) { int l = loc - T_QR;   n = l >> 8; k0 = l & 255; src = pwqr;  sN = 64;   klim = 256; nok = 1; }
        else                  { int l = loc - T_UKV;  n = l / 384; k0 = l % 384; src = pwukv; sN = 1024; klim = 341; nok = 1; }
        u16 out[8];
        #pragma unroll
        for (int j = 0; j < 8; ++j) {
            int k = k0 + j;
            out[j] = (nok && k < klim) ? rdu(src, k * sN + n) : (u16)0;
        }
        *(uint4*)&WT[loc] = *(uint4*)out;
    }
}

// ---------- rope epilogue ----------
static __device__ __forceinline__ void rope_epi(
    f32x4 (&acc)[2][4], bf16* __restrict__ dst, int m0, int w, int g, int lr, int tid, bool scaleq)
{
    const float SCv = 0.11785113019775793f;   // 1/sqrt(72)
    #pragma unroll
    for (int mt = 0; mt < 2; ++mt)
    #pragma unroll
    for (int r = 0; r < 4; ++r) {
        int gm = m0 + w * 32 + mt * 16 + g * 4 + r;
        int s = gm & 2047, b = gm >> 11;
        float ang = (float)s * exp2f(-(float)(lr & 3) * 3.3219280948873623f);
        float sn, cs;
        sincosf(ang, &sn, &cs);
        #pragma unroll
        for (int nt = 0; nt < 4; ++nt) {
            float v = acc[mt][nt][r];
            float pt = __shfl_xor(v, 4);
            float o = (lr & 4) ? fmaf(pt, sn, v * cs) : fmaf(-pt, sn, v * cs);
            if (scaleq) o *= SCv;
            int h = (nt * 16 + lr) >> 3, j = lr & 7;
            dst[((size_t)(b * NH + h) * SEQ + s) * DQKPAD + 64 + j] = __float2bfloat16(o);
        }
    }
    for (int u = tid; u < 128 * 96; u += 256) {
        int rw = u / 96, rem = u - rw * 96;
        int h = rem / 12, c = rem - h * 12;
        int row = m0 + rw, b2 = row >> 11, s2 = row & 2047;
        *(unsigned int*)&dst[((size_t)(b2 * NH + h) * SEQ + s2) * DQKPAD + 72 + c * 2] = 0u;
    }
}

// ------- 128x64 bf16 MFMA GEMM body (f32o passed directly) -------
static __device__ __forceinline__ void gemm_body(
    int bx, int by,
    const bf16* __restrict__ A, int lda,
    const bf16* __restrict__ BT, int ldb,
    int N, int Kpad, int mode,
    void* __restrict__ C0, int ldc,
    bf16* __restrict__ kv_k, bf16* __restrict__ kv_v,
    int f32o, float* __restrict__ C0f,
    bf16* LB)
{
    bf16* Al = LB;
    bf16* Bl = LB + 128 * 64;
    const int tid = threadIdx.x;
    const int m0 = by * 128, n0 = bx * 64;
    const int lane = tid & 63, w = tid >> 6;
    const int g = lane >> 4, lr = lane & 15;
    f32x4 acc[2][4] = {};
    const int r8 = lane >> 3;
    const int xr8 = ((lane & 7) ^ r8) * 8;
    const int swx = (lr & 7) << 4;

    __syncthreads();   // LDS reuse fence across virtual blocks
    for (int k0 = 0; k0 < Kpad; k0 += 64) {
        #pragma unroll
        for (int i = 0; i < 4; ++i)
            GL16(&A[(size_t)(m0 + w * 32 + i * 8 + r8) * lda + k0 + xr8],
                 (char*)Al + w * 4096 + i * 1024);
        #pragma unroll
        for (int i = 0; i < 2; ++i)
            GL16(&BT[(size_t)(n0 + w * 16 + i * 8 + r8) * ldb + k0 + xr8],
                 (char*)Bl + w * 2048 + i * 1024);
        __syncthreads();
        #pragma unroll
        for (int ks = 0; ks < 2; ++ks) {
            const int cs = (ks * 64 + g * 16) ^ swx;
            bf16x8 a0 = ld_bf8((const bf16*)((const char*)Al + (w * 32 + lr) * 128 + cs));
            bf16x8 a1 = ld_bf8((const bf16*)((const char*)Al + (w * 32 + 16 + lr) * 128 + cs));
            #pragma unroll
            for (int nt = 0; nt < 4; ++nt) {
                bf16x8 b = ld_bf8((const bf16*)((const char*)Bl + (nt * 16 + lr) * 128 + cs));
                acc[0][nt] = __builtin_amdgcn_mfma_f32_16x16x32_bf16(a0, b, acc[0][nt], 0, 0, 0);
                acc[1][nt] = __builtin_amdgcn_mfma_f32_16x16x32_bf16(a1, b, acc[1][nt], 0, 0, 0);
            }
        }
        __syncthreads();
    }

    if (mode == 0 && n0 == 640) {       // kr-rope block -> k_attn
        rope_epi(acc, kv_k, m0, w, g, lr, tid, false);
        return;
    }
    if (mode == 4 && n0 == DM) {        // qr-rope block (scaled) -> q_attn
        rope_epi(acc, (bf16*)C0, m0, w, g, lr, tid, true);
        return;
    }
    if (mode == 3 && n0 >= DM) {
        const int h = (n0 - DM) >> 6;
        const int b = m0 >> 11, s0 = m0 & 2047;
        bf16* T = LB;   // [64][136]
        #pragma unroll
        for (int mt = 0; mt < 2; ++mt)
        #pragma unroll
        for (int nt = 0; nt < 4; ++nt)
        #pragma unroll
        for (int r = 0; r < 4; ++r) {
            int dv = nt * 16 + lr;
            int sl = w * 32 + mt * 16 + g * 4 + r;
            T[dv * 136 + sl] = __float2bfloat16(acc[mt][nt][r]);
        }
        __syncthreads();
        const int row = tid >> 2, coff = (tid & 3) * 32;
        bf16* dst = &kv_v[((size_t)(b * NH + h) * DHD + row) * SEQ + s0 + coff];
        const bf16* srcp = &T[row * 136 + coff];
        #pragma unroll
        for (int q2 = 0; q2 < 4; ++q2)
            *(uint4*)(dst + q2 * 8) = *(const uint4*)(srcp + q2 * 8);
        return;
    }

    const float SCv = 0.11785113019775793f;
    #pragma unroll
    for (int mt = 0; mt < 2; ++mt)
    #pragma unroll
    for (int nt = 0; nt < 4; ++nt)
    #pragma unroll
    for (int r = 0; r < 4; ++r) {
        int gm = m0 + w * 32 + mt * 16 + g * 4 + r;
        int gn = n0 + nt * 16 + lr;
        float v = acc[mt][nt][r];
        if (mode == 0) {
            ((bf16*)C0)[(size_t)gm * ldc + gn] = __float2bfloat16(v);
        } else if (mode == 1) {
            if (f32o) C0f[(size_t)gm * ldc + gn] = v;
            else ((bf16*)C0)[(size_t)gm * ldc + gn] = __float2bfloat16(v);
        } else if (mode == 4) {
            int b = gm >> 11, s = gm & 2047;
            int h = gn >> 6, dh = gn & 63;
            ((bf16*)C0)[((size_t)(b * NH + h) * SEQ + s) * DQKPAD + dh] = __float2bfloat16(v * SCv);
        } else {
            int b = gm >> 11, s = gm & 2047;
            int h = gn >> 6, dh = gn & 63;
            kv_k[((size_t)(b * NH + h) * SEQ + s) * DQKPAD + dh] = __float2bfloat16(v);
        }
    }
}

// ------- merged layernorms body -------
static __device__ __forceinline__ void ln_body(
    int blk, int f,
    const bf16* __restrict__ y,
    const bf16* __restrict__ qg, const bf16* __restrict__ qb,
    const bf16* __restrict__ kg, const bf16* __restrict__ kb,
    bf16* __restrict__ cq, bf16* __restrict__ ckv_b, float* __restrict__ ckv_f,
    bf16* __restrict__ ckvp)
{
    const int w = threadIdx.x >> 6, lane = threadIdx.x & 63;
    if (blk < 1024) {
        const int row = blk * 4 + w;
        const bf16* yr = y + (size_t)row * 704;
        float s = 0.f, ss = 0.f;
        for (int i = lane; i < 256; i += 64) { float v = __bfloat162float(yr[i]); s += v; ss += v * v; }
        #pragma unroll
        for (int m = 1; m < 64; m <<= 1) { s += __shfl_xor(s, m); ss += __shfl_xor(ss, m); }
        float mean = s * (1.f / 256.f);
        float var = ss * (1.f / 256.f) - mean * mean;
        float rstd = rsqrtf(var + 1e-5f);
        for (int i = lane; i < 256; i += 64) {
            float v = (__bfloat162float(yr[i]) - mean) * rstd * __bfloat162float(qg[i]) + __bfloat162float(qb[i]);
            cq[(size_t)row * 256 + i] = __float2bfloat16(v);
        }
    } else {
        const int row = (blk - 1024) * 4 + w;
        const bf16* yr = y + (size_t)row * 704 + 256;
        float s = 0.f, ss = 0.f;
        for (int i = lane; i < KVP; i += 64) { float v = __bfloat162float(yr[i]); s += v; ss += v * v; }
        #pragma unroll
        for (int m = 1; m < 64; m <<= 1) { s += __shfl_xor(s, m); ss += __shfl_xor(ss, m); }
        float mean = s * (1.f / 341.f);
        float var = ss * (1.f / 341.f) - mean * mean;
        float rstd = rsqrtf(var + 1e-5f);
        for (int i = lane; i < KVP; i += 64) {
            float v = (__bfloat162float(yr[i]) - mean) * rstd * __bfloat162float(kg[i]) + __bfloat162float(kb[i]);
            if (f) ckv_f[(size_t)row * KVP + i] = v;
            else ckv_b[(size_t)row * KVP + i] = __float2bfloat16(v);
            ckvp[(size_t)row * 384 + i] = __float2bfloat16(v);
        }
        for (int i = KVP + lane; i < 384; i += 64) ckvp[(size_t)row * 384 + i] = __float2bfloat16(0.f);
    }
}

// ---- attention body ----
static __device__ __forceinline__ void attn_body(
    int sp, int pr, int bh,
    const bf16* __restrict__ qa, const bf16* __restrict__ ka, const bf16* __restrict__ vat,
    bf16* __restrict__ po, float* __restrict__ mlm, float* __restrict__ mll,
    char* SMRAW)
{
    bf16* Kl = (bf16*)SMRAW;                    // [64][128]
    bf16* Vt = (bf16*)(SMRAW + 16384);          // [64][72]
    bf16* Pl = (bf16*)(SMRAW + 25600);          // [4][16][72]
    const int tid = threadIdx.x, w = tid >> 6, lane = tid & 63;
    const int g = lane >> 4, lr = lane & 15;
    const size_t base = (size_t)bh * SEQ;
    const float L2E = 1.4426950408889634f;
    const bf16* vb = vat + (size_t)bh * DHD * SEQ;

    uint4 kreg0, kreg1, kreg2, vreg0, vreg1;
    const int vd = tid >> 2, vko = (tid & 3) * 16;
    const int kr0 = tid / 12,          ks0 = tid % 12;
    const int kr1 = (tid + 256) / 12,  ks1 = (tid + 256) % 12;
    const int kr2 = (tid + 512) / 12,  ks2 = (tid + 512) % 12;
    const int kx0 = (ks0 ^ (kr0 & 15)) * 8;
    const int kx1 = (ks1 ^ (kr1 & 15)) * 8;
    const int kx2 = (ks2 ^ (kr2 & 15)) * 8;

    #define ISSUE_KV(j0)  do { \
        kreg0 = *(const uint4*)&ka[(base + (j0) + kr0) * DQKPAD + ks0 * 8]; \
        kreg1 = *(const uint4*)&ka[(base + (j0) + kr1) * DQKPAD + ks1 * 8]; \
        kreg2 = *(const uint4*)&ka[(base + (j0) + kr2) * DQKPAD + ks2 * 8]; \
        const bf16* vsrc = &vb[(size_t)vd * SEQ + (j0) + vko]; \
        vreg0 = *(const uint4*)vsrc; vreg1 = *(const uint4*)(vsrc + 8); \
    } while (0)

    for (int half = 0; half < 2; ++half) {
        const int qb = half ? (31 - pr) : pr;
        const int qrow0 = qb * 64 + w * 16;
        const int myq = qrow0 + lr;

        bf16x8 qf[3];
        #pragma unroll
        for (int kc = 0; kc < 3; ++kc)
            qf[kc] = ld_bf8(&qa[(base + myq) * DQKPAD + kc * 32 + g * 8]);

        float m_p = -1e30f, l_p = 0.f;
        f32x4 acc_o[4] = {};
        const int ng = qb + 1;
        const int bs = (ng * sp) >> 2, be = (ng * (sp + 1)) >> 2;

        if (bs < be) ISSUE_KV(bs * 64);

        for (int gi = bs; gi < be; ++gi) {
            const int j0 = gi * 64;
            __syncthreads();
            *(uint4*)&Kl[kr0 * 128 + kx0] = kreg0;
            *(uint4*)&Kl[kr1 * 128 + kx1] = kreg1;
            *(uint4*)&Kl[kr2 * 128 + kx2] = kreg2;
            *(uint4*)&Vt[vd * 72 + vko]     = vreg0;
            *(uint4*)&Vt[vd * 72 + vko + 8] = vreg1;
            __syncthreads();
            if (gi + 1 < be) ISSUE_KV(j0 + 64);

            f32x4 accs[4] = {};
            __builtin_amdgcn_s_setprio(1);
            #pragma unroll
            for (int kc = 0; kc < 3; ++kc) {
                #pragma unroll
                for (int nt = 0; nt < 4; ++nt) {
                    bf16x8 kf = ld_bf8(&Kl[(nt * 16 + lr) * 128 + ((kc * 4 + g) ^ lr) * 8]);
                    accs[nt] = __builtin_amdgcn_mfma_f32_16x16x32_bf16(kf, qf[kc], accs[nt], 0, 0, 0);
                }
            }
            __builtin_amdgcn_s_setprio(0);
            float s_[4][4];
            float mloc = -1e30f;
            if (j0 + 63 > qrow0) {
                #pragma unroll
                for (int nt = 0; nt < 4; ++nt)
                #pragma unroll
                for (int r = 0; r < 4; ++r) {
                    int key = j0 + nt * 16 + g * 4 + r;
                    float sv = accs[nt][r];
                    sv = (key <= myq) ? sv : -1e30f;
                    s_[nt][r] = sv;
                    mloc = fmaxf(mloc, sv);
                }
            } else {
                #pragma unroll
                for (int nt = 0; nt < 4; ++nt)
                #pragma unroll
                for (int r = 0; r < 4; ++r) {
                    float sv = accs[nt][r];
                    s_[nt][r] = sv;
                    mloc = fmaxf(mloc, sv);
                }
            }
            mloc = fmaxf(mloc, __shfl_xor(mloc, 16));
            mloc = fmaxf(mloc, __shfl_xor(mloc, 32));

            if (__all(mloc <= m_p + 8.f)) {
                float rs = 0.f;
                #pragma unroll
                for (int nt = 0; nt < 4; ++nt)
                #pragma unroll
                for (int r = 0; r < 4; ++r) {
                    float p = exp2f((s_[nt][r] - m_p) * L2E);
                    s_[nt][r] = p; rs += p;
                }
                rs += __shfl_xor(rs, 16);
                rs += __shfl_xor(rs, 32);
                l_p += rs;
            } else {
                float mn = fmaxf(m_p, mloc);
                float alpha = exp2f((m_p - mn) * L2E);
                m_p = mn;
                float rs = 0.f;
                #pragma unroll
                for (int nt = 0; nt < 4; ++nt)
                #pragma unroll
                for (int r = 0; r < 4; ++r) {
                    float p = exp2f((s_[nt][r] - mn) * L2E);
                    s_[nt][r] = p; rs += p;
                }
                rs += __shfl_xor(rs, 16);
                rs += __shfl_xor(rs, 32);
                l_p = l_p * alpha + rs;
                float ar[4];
                #pragma unroll
                for (int r = 0; r < 4; ++r) ar[r] = __shfl(alpha, g * 4 + r);
                #pragma unroll
                for (int nv = 0; nv < 4; ++nv)
                #pragma unroll
                for (int r = 0; r < 4; ++r) acc_o[nv][r] *= ar[r];
            }
            #pragma unroll
            for (int nt = 0; nt < 4; ++nt) {
                ushort4 pk;
                pk.x = __builtin_bit_cast(u16, __float2bfloat16(s_[nt][0]));
                pk.y = __builtin_bit_cast(u16, __float2bfloat16(s_[nt][1]));
                pk.z = __builtin_bit_cast(u16, __float2bfloat16(s_[nt][2]));
                pk.w = __builtin_bit_cast(u16, __float2bfloat16(s_[nt][3]));
                *(ushort4*)&Pl[(w * 16 + lr) * 72 + nt * 16 + g * 4] = pk;
            }
            bf16x8 pf0 = ld_bf8(&Pl[(w * 16 + lr) * 72 + g * 8]);
            bf16x8 pf1 = ld_bf8(&Pl[(w * 16 + lr) * 72 + 32 + g * 8]);
            __builtin_amdgcn_s_setprio(1);
            #pragma unroll
            for (int nv = 0; nv < 4; ++nv) {
                bf16x8 vf0 = ld_bf8(&Vt[(nv * 16 + lr) * 72 + g * 8]);
                acc_o[nv] = __builtin_amdgcn_mfma_f32_16x16x32_bf16(pf0, vf0, acc_o[nv], 0, 0, 0);
                bf16x8 vf1 = ld_bf8(&Vt[(nv * 16 + lr) * 72 + 32 + g * 8]);
                acc_o[nv] = __builtin_amdgcn_mfma_f32_16x16x32_bf16(pf1, vf1, acc_o[nv], 0, 0, 0);
            }
            __builtin_amdgcn_s_setprio(0);
        }

        const size_t pb = (size_t)(bh * NSPLIT + sp) * SEQ;
        #pragma unroll
        for (int r = 0; r < 4; ++r) {
            int qrow = qrow0 + g * 4 + r;
            #pragma unroll
            for (int nv = 0; nv < 4; ++nv)
                po[(pb + qrow) * DHD + nv * 16 + lr] = __float2bfloat16(acc_o[nv][r]);
        }
        if (lane < 16) {
            size_t mi = ((size_t)bh * SEQ + qrow0 + lane) * 4 + sp;
            mlm[mi] = m_p;
            mll[mi] = l_p;
        }
    }
    #undef ISSUE_KV
}

// ---------------- combine body ----------------
static __device__ __forceinline__ void combine_body(
    int id, const bf16* __restrict__ po, const float* __restrict__ mlm, const float* __restrict__ mll,
    bf16* __restrict__ ao)
{
    int bh = id >> 14;
    int rem = id & 16383;
    int q = rem >> 3, dc = (rem & 7) * 8;
    const float L2E = 1.4426950408889634f;
    size_t mi = ((size_t)bh * SEQ + q) * 4;
    f32x4 ms = *(const f32x4*)&mlm[mi];
    f32x4 ls = *(const f32x4*)&mll[mi];
    float M = fmaxf(fmaxf(ms[0], ms[1]), fmaxf(ms[2], ms[3]));
    float wsc[NSPLIT]; float L = 0.f;
    #pragma unroll
    for (int s = 0; s < NSPLIT; ++s) { wsc[s] = exp2f((ms[s] - M) * L2E); L += wsc[s] * ls[s]; }
    float o[8] = {};
    #pragma unroll
    for (int s = 0; s < NSPLIT; ++s) {
        if (ls[s] <= 0.f) continue;
        bf16x8 pv = ld_bf8(&po[((size_t)(bh * NSPLIT + s) * SEQ + q) * DHD + dc]);
        #pragma unroll
        for (int j = 0; j < 8; ++j) o[j] += wsc[s] * (float)pv[j];
    }
    float invL = 1.f / L;
    int b = bh >> 3, h = bh & 7;
    __bf16 tmp[8];
    #pragma unroll
    for (int j = 0; j < 8; ++j) tmp[j] = (__bf16)(o[j] * invL);
    *(uint4*)&ao[((size_t)(b * SEQ) + q) * DM + h * DHD + dc] = *(uint4*)tmp;
}

// ---------- dtype flag helper ----------
static __device__ __forceinline__ int detect_f(const void* px, int* cntp) {
    const int tid = threadIdx.x;
    if (tid == 0) *cntp = 0;
    __syncthreads();
    int bad = 0;
    const u16* xs = (const u16*)px;
    for (int i = tid; i < 2048; i += 256) {
        u16 u = xs[i];
        int e = (u >> 7) & 0xFF;
        if (u != 0 && (e < 90 || e > 164)) bad++;
    }
    #pragma unroll
    for (int m2 = 1; m2 < 64; m2 <<= 1) bad += __shfl_xor(bad, m2);
    if ((tid & 63) == 0) atomicAdd(cntp, bad);
    __syncthreads();
    return (*cntp > 256) ? 1 : 0;
}

// ================= cooperative mega-kernel =================
__global__ __launch_bounds__(256) void mega(
    const void* px, const void* pwdq, const void* pwuq, const void* pwqr,
    const void* pwdkv, const void* pwukv, const void* pwkr, const void* pwo,
    const void* pqg, const void* pqb, const void* pkg, const void* pkb,
    u16* arena, u16* WTu, bf16* y, bf16* cq, bf16* ckvp,
    bf16* q_attn, bf16* k_attn, bf16* v_attnT, bf16* attn_o, bf16* po,
    float* mlm, float* mll, bf16* out_b, float* out_f, bf16* ckv_b, float* ckv_f)
{
    cg::grid_group grid = cg::this_grid();
    __shared__ __align__(16) char SMRAW[34816];
    bf16* SM = (bf16*)SMRAW;
    __shared__ int cnt;
    const int f = detect_f(px, &cnt);

    const bf16* WT = (const bf16*)WTu;
    const bf16* xb  = (const bf16*)arena + OFF_X;
    const bf16* W_o = (const bf16*)arena + OFF_WO;
    const bf16* qg  = (const bf16*)arena + OFF_QG;
    const bf16* qb_ = (const bf16*)arena + OFF_QB;
    const bf16* kg  = (const bf16*)arena + OFF_KG;
    const bf16* kb  = (const bf16*)arena + OFF_KB;

    for (int vb = blockIdx.x; vb < NPREPB; vb += gridDim.x) {
        int gid = vb * 256 + threadIdx.x;
        if (gid < G_TOT)
            prep_work(gid, f, px, pwdq, pwuq, pwqr, pwdkv, pwukv, pwkr, pwo,
                      pqg, pqb, pkg, pkb, arena, WTu);
    }
    grid.sync();

    for (int vb = blockIdx.x; vb < 352; vb += gridDim.x)
        gemm_body(vb % 11, vb / 11, xb, DM, WT + T_DQ, DM, 704, DM, 0,
                  y, 704, k_attn, nullptr, 0, nullptr, SM);
    grid.sync();

    for (int vb = blockIdx.x; vb < 2048; vb += gridDim.x)
        ln_body(vb, f, y, qg, qb_, kg, kb, cq, ckv_b, ckv_f, ckvp);
    grid.sync();

    for (int vb = blockIdx.x; vb < 800; vb += gridDim.x) {
        int bxv = vb % 25, by = vb / 25;
        if (bxv < 9)
            gemm_body(bxv, by, cq, QP, WT + T_UQ, QP, 576, QP, 4,
                      q_attn, 0, nullptr, nullptr, 0, nullptr, SM);
        else
            gemm_body(bxv - 9, by, ckvp, 384, WT + T_UKV, 384, 1024, 384, 3,
                      nullptr, 0, k_attn, v_attnT, 0, nullptr, SM);
    }
    grid.sync();

    for (int vb = blockIdx.x; vb < 1024; vb += gridDim.x) {
        int sp = vb & 3, rest = vb >> 2;
        int pr = rest & 15, bh = rest >> 4;
        attn_body(sp, pr, bh, q_attn, k_attn, v_attnT, po, mlm, mll, SMRAW);
    }
    grid.sync();

    for (int vb = blockIdx.x; vb < 1024; vb += gridDim.x)
        combine_body(vb * 256 + threadIdx.x, po, mlm, mll, attn_o);
    grid.sync();

    for (int vb = blockIdx.x; vb < 256; vb += gridDim.x)
        gemm_body(vb % 8, vb / 8, attn_o, DM, W_o, DM, DM, DM, 1,
                  out_b, DM, nullptr, nullptr, f, out_f, SM);
}

// ================= fallback kernels (r18 path) =================
__global__ __launch_bounds__(256) void prep_k(
    const void* px, const void* pwdq, const void* pwuq, const void* pwqr,
    const void* pwdkv, const void* pwukv, const void* pwkr, const void* pwo,
    const void* pqg, const void* pqb, const void* pkg, const void* pkb,
    u16* __restrict__ arena, u16* __restrict__ WT, int* __restrict__ flagp)
{
    __shared__ int cnt;
    const int f = detect_f(px, &cnt);
    if (blockIdx.x == 0 && threadIdx.x == 0) *flagp = f;
    int gid = blockIdx.x * 256 + threadIdx.x;
    if (gid >= G_TOT) return;
    prep_work(gid, f, px, pwdq, pwuq, pwqr, pwdkv, pwukv, pwkr, pwo,
              pqg, pqb, pkg, pkb, arena, WT);
}

__global__ __launch_bounds__(256) void gemm128(
    const bf16* __restrict__ A, int lda,
    const bf16* __restrict__ BT, int ldb,
    int N, int Kpad, int mode,
    void* __restrict__ C0, int ldc,
    bf16* __restrict__ kv_k, bf16* __restrict__ kv_v,
    const int* __restrict__ flagp, float* __restrict__ C0f)
{
    __shared__ __align__(16) bf16 LB[128 * 64 + 64 * 64];
    const int f32o = (mode == 1 && flagp) ? *flagp : 0;
    gemm_body(blockIdx.x, blockIdx.y, A, lda, BT, ldb, N, Kpad, mode,
              C0, ldc, kv_k, kv_v, f32o, C0f, LB);
}

__global__ __launch_bounds__(256) void gemm_dual(
    const bf16* __restrict__ A1, const bf16* __restrict__ BT1, void* __restrict__ C1,
    const bf16* __restrict__ A2, const bf16* __restrict__ BT2,
    bf16* __restrict__ kv_k, bf16* __restrict__ kv_v)
{
    __shared__ __align__(16) bf16 LB[128 * 64 + 64 * 64];
    if (blockIdx.x < 9) {
        gemm_body(blockIdx.x, blockIdx.y, A1, QP, BT1, QP, 576, QP, 4,
                  C1, 0, nullptr, nullptr, 0, nullptr, LB);
    } else {
        gemm_body(blockIdx.x - 9, blockIdx.y, A2, 384, BT2, 384, 1024, 384, 3,
                  nullptr, 0, kv_k, kv_v, 0, nullptr, LB);
    }
}

__global__ __launch_bounds__(256) void ln_both(
    const bf16* __restrict__ y,
    const bf16* __restrict__ qg, const bf16* __restrict__ qb,
    const bf16* __restrict__ kg, const bf16* __restrict__ kb,
    bf16* __restrict__ cq, bf16* __restrict__ ckv_b, float* __restrict__ ckv_f,
    bf16* __restrict__ ckvp, const int* __restrict__ flagp)
{
    ln_body(blockIdx.x, *flagp, y, qg, qb, kg, kb, cq, ckv_b, ckv_f, ckvp);
}

__global__ __launch_bounds__(256) void attn_split3(
    const bf16* __restrict__ qa, const bf16* __restrict__ ka, const bf16* __restrict__ vat,
    bf16* __restrict__ po, float* __restrict__ mlm, float* __restrict__ mll)
{
    __shared__ __align__(16) char SMRAW[34816];
    attn_body(blockIdx.x, blockIdx.y, blockIdx.z, qa, ka, vat, po, mlm, mll, SMRAW);
}

__global__ __launch_bounds__(256) void attn_combine(
    const bf16* __restrict__ po, const float* __restrict__ mlm, const float* __restrict__ mll,
    bf16* __restrict__ ao)
{
    combine_body(blockIdx.x * 256 + threadIdx.x, po, mlm, mll, ao);
}

extern "C" void kernel_launch(void* const* d_in, const int* in_sizes, int n_in,
                              void* d_out, int out_size, void* d_ws, size_t ws_size,
                              hipStream_t stream) {
    char* ws = (char*)d_ws;
    u16*  arena   = (u16*)(ws + 0);
    float* ml_m   = (float*)(ws + 0);             // alias x region, 512KB
    float* ml_l   = (float*)(ws + 1048576);       // 512KB
    u16*  WTu     = (u16*)(ws + 6391296);
    int*  flagp   = (int*)(ws + 8193536);
    bf16* y       = (bf16*)(ws + 8194048);
    bf16* cq      = (bf16*)(ws + 19728384);
    bf16* ckvp    = (bf16*)(ws + 21825536);
    bf16* q_attn  = (bf16*)(ws + 26019840);
    bf16* k_attn  = (bf16*)(ws + 32311296);
    bf16* v_attnT = (bf16*)(ws + 38602752);
    bf16* attn_o  = (bf16*)(ws + 42797056);
    bf16* po      = (bf16*)(ws + 50331648);

    const void* px    = d_in[0];
    const void* pwdq  = d_in[1];
    const void* pwuq  = d_in[2];
    const void* pwqr  = d_in[3];
    const void* pwdkv = d_in[4];
    const void* pwukv = d_in[5];
    const void* pwkr  = d_in[6];
    const void* pwo   = d_in[7];
    const void* pqg   = d_in[8];
    const void* pqb   = d_in[9];
    const void* pkg   = d_in[10];
    const void* pkb   = d_in[11];

    bf16*  out_b = (bf16*)d_out;
    float* out_f = (float*)d_out;
    bf16*  ckv_b = out_b + (size_t)MROWS * DM;
    float* ckv_f = out_f + (size_t)MROWS * DM;

    void* args[] = {
        &px, &pwdq, &pwuq, &pwqr, &pwdkv, &pwukv, &pwkr, &pwo,
        &pqg, &pqb, &pkg, &pkb,
        &arena, &WTu, &y, &cq, &ckvp,
        &q_attn, &k_attn, &v_attnT, &attn_o, &po,
        &ml_m, &ml_l, &out_b, &out_f, &ckv_b, &ckv_f
    };
    hipError_t err = hipLaunchCooperativeKernel((const void*)mega, dim3(NBLK), dim3(256), args, 0, stream);
    if (err == hipSuccess) return;

    // ---- fallback: proven 7-dispatch path ----
    const bf16* AR  = (const bf16*)arena;
    const bf16* xb  = AR + OFF_X;
    const bf16* W_o = AR + OFF_WO;
    const bf16* qg  = AR + OFF_QG;
    const bf16* qb_ = AR + OFF_QB;
    const bf16* kg  = AR + OFF_KG;
    const bf16* kb  = AR + OFF_KB;
    const bf16* WT  = (const bf16*)WTu;

    dim3 blk(256);
    prep_k<<<dim3((G_TOT + 255) / 256), blk, 0, stream>>>(
        px, pwdq, pwuq, pwqr, pwdkv, pwukv, pwkr, pwo,
        pqg, pqb, pkg, pkb, arena, WTu, flagp);
    gemm128<<<dim3(11, 32), blk, 0, stream>>>(xb, DM, WT + T_DQ, DM, 704, DM, 0, y, 704, k_attn, nullptr, nullptr, nullptr);
    ln_both<<<dim3(2048), blk, 0, stream>>>(y, qg, qb_, kg, kb, cq, ckv_b, ckv_f, ckvp, flagp);
    gemm_dual<<<dim3(25, 32), blk, 0, stream>>>(cq, WT + T_UQ, q_attn, ckvp, WT + T_UKV, k_attn, v_attnT);
    attn_split3<<<dim3(NSPLIT, 16, 16), blk, 0, stream>>>(q_attn, k_attn, v_attnT, po, ml_m, ml_l);
    attn_combine<<<dim3(1024), blk, 0, stream>>>(po, ml_m, ml_l, attn_o);
    gemm128<<<dim3(8, 32), blk, 0, stream>>>(attn_o, DM, W_o, DM, DM, DM, 1, out_b, DM, nullptr, nullptr, flagp, out_f);
}

// Round 20
// 110.111 us; speedup vs baseline: 3.1339x; 3.1339x over previous
//
#include <hip/hip_runtime.h>
#include <hip/hip_bf16.h>

#define BATCH 2
#define SEQ 2048
#define DM 512
#define NH 8
#define DHD 64
#define QP 256
#define KVP 341
#define DQKPAD 96
#define MROWS 4096   // BATCH*SEQ

// bf16 arena element offsets (x, W_o, LN params only)
#define OFF_X     0
#define OFF_WO    2932224
#define OFF_QG    3194368
#define OFF_QB    3194624
#define OFF_KG    3194880
#define OFF_KB    3195221

// transposed-weight arena element offsets ([N][K])
#define T_DQ   0        // [256][512]
#define T_DKV  131072   // [384][512] (n>=341 zero)
#define T_KR   327680   // [64][512]
#define T_UQ   360448   // [512][256]
#define T_QR   491520   // [64][256]
#define T_UKV  507904   // [1024][384] (k>=341 zero)
#define T_TOT  901120

#define NW_X   2097152
#define NW_WO  262144
#define NW_PAR 1194

// prep work groups (8 elems each)
#define G_X   262144
#define G_WO  32768
#define G_PAR 150
#define G_WT  112640
#define G_TOT (G_X + G_WO + G_PAR + G_WT)

#define NSPLIT 4

typedef __bf16 bf16x8 __attribute__((ext_vector_type(8)));
typedef float f32x4 __attribute__((ext_vector_type(4)));
typedef __hip_bfloat16 bf16;
typedef unsigned short u16;

static __device__ __forceinline__ bf16x8 ld_bf8(const bf16* p) {
    return __builtin_bit_cast(bf16x8, *(const uint4*)p);
}

// async global->LDS, 16B per lane; LDS dest = wave-uniform base + lane*16
#define GL16(gp, lp) __builtin_amdgcn_global_load_lds( \
    (const __attribute__((address_space(1))) void*)(gp), \
    (__attribute__((address_space(3))) void*)(lp), 16, 0, 0)

// ---------- prep: dtype-flag + convert x/W_o/params + weight transposes (8-wide) ----------
__global__ __launch_bounds__(256) void prep(
    const void* px, const void* pwdq, const void* pwuq, const void* pwqr,
    const void* pwdkv, const void* pwukv, const void* pwkr, const void* pwo,
    const void* pqg, const void* pqb, const void* pkg, const void* pkb,
    u16* __restrict__ arena, u16* __restrict__ WT, int* __restrict__ flagp)
{
    __shared__ int cnt;
    if (threadIdx.x == 0) cnt = 0;
    __syncthreads();
    int bad = 0;
    const u16* xs = (const u16*)px;
    for (int i = threadIdx.x; i < 2048; i += 256) {
        u16 u = xs[i];
        int e = (u >> 7) & 0xFF;
        if (u != 0 && (e < 90 || e > 164)) bad++;
    }
    #pragma unroll
    for (int m2 = 1; m2 < 64; m2 <<= 1) bad += __shfl_xor(bad, m2);
    if ((threadIdx.x & 63) == 0) atomicAdd(&cnt, bad);
    __syncthreads();
    const int f = (cnt > 256) ? 1 : 0;   // 1 => inputs are fp32
    if (blockIdx.x == 0 && threadIdx.x == 0) *flagp = f;

    int gid = blockIdx.x * 256 + threadIdx.x;
    if (gid >= G_TOT) return;

    auto rdu = [&](const void* s, int i) -> u16 {
        if (f) return __builtin_bit_cast(u16, __float2bfloat16(((const float*)s)[i]));
        return ((const u16*)s)[i];
    };

    if (gid < G_X + G_WO) {
        const void* src = (gid < G_X) ? px : pwo;
        int base = (gid < G_X) ? OFF_X : OFF_WO;
        int i = (gid < G_X) ? gid : gid - G_X;
        u16 out[8];
        if (f) {
            const float* s = (const float*)src + i * 8;
            #pragma unroll
            for (int j = 0; j < 8; ++j) out[j] = __builtin_bit_cast(u16, __float2bfloat16(s[j]));
        } else {
            *(uint4*)out = ((const uint4*)src)[i];
        }
        *(uint4*)&arena[base + i * 8] = *(uint4*)out;
    } else if (gid < G_X + G_WO + G_PAR) {
        int i0 = (gid - G_X - G_WO) * 8;
        for (int j = 0; j < 8; ++j) {
            int i = i0 + j;
            if (i >= NW_PAR) break;
            if (i < 256)      arena[OFF_QG + i]         = rdu(pqg, i);
            else if (i < 512) arena[OFF_QB + (i - 256)] = rdu(pqb, i - 256);
            else if (i < 853) arena[OFF_KG + (i - 512)] = rdu(pkg, i - 512);
            else              arena[OFF_KB + (i - 853)] = rdu(pkb, i - 853);
        }
    } else {
        int loc = (gid - (G_X + G_WO + G_PAR)) * 8;   // 8 consecutive: same n, k0..k0+7
        const void* src; int n, k0, sN, klim, nok;
        if (loc < T_DKV)      { int l = loc;          n = l >> 9; k0 = l & 511; src = pwdq;  sN = 256;  klim = 512; nok = 1; }
        else if (loc < T_KR)  { int l = loc - T_DKV;  n = l >> 9; k0 = l & 511; src = pwdkv; sN = 341;  klim = 512; nok = (n < 341); }
        else if (loc < T_UQ)  { int l = loc - T_KR;   n = l >> 9; k0 = l & 511; src = pwkr;  sN = 64;   klim = 512; nok = 1; }
        else if (loc < T_QR)  { int l = loc - T_UQ;   n = l >> 8; k0 = l & 255; src = pwuq;  sN = 512;  klim = 256; nok = 1; }
        else if (loc < T_UKV) { int l = loc - T_QR;   n = l >> 8; k0 = l & 255; src = pwqr;  sN = 64;   klim = 256; nok = 1; }
        else                  { int l = loc - T_UKV;  n = l / 384; k0 = l % 384; src = pwukv; sN = 1024; klim = 341; nok = 1; }
        u16 out[8];
        #pragma unroll
        for (int j = 0; j < 8; ++j) {
            int k = k0 + j;
            out[j] = (nok && k < klim) ? rdu(src, k * sN + n) : (u16)0;
        }
        *(uint4*)&WT[loc] = *(uint4*)out;
    }
}

// ---------- rope epilogue: acc holds 64 rope cols for 128 rows; partner via shfl ----------
static __device__ __forceinline__ void rope_epi(
    f32x4 (&acc)[2][4], bf16* __restrict__ dst, int m0, int w, int g, int lr, int tid, bool scaleq)
{
    const float SCv = 0.11785113019775793f;   // 1/sqrt(72)
    #pragma unroll
    for (int mt = 0; mt < 2; ++mt)
    #pragma unroll
    for (int r = 0; r < 4; ++r) {
        int gm = m0 + w * 32 + mt * 16 + g * 4 + r;
        int s = gm & 2047, b = gm >> 11;
        float ang = (float)s * exp2f(-(float)(lr & 3) * 3.3219280948873623f);
        float sn, cs;
        sincosf(ang, &sn, &cs);
        #pragma unroll
        for (int nt = 0; nt < 4; ++nt) {
            float v = acc[mt][nt][r];
            float pt = __shfl_xor(v, 4);
            float o = (lr & 4) ? fmaf(pt, sn, v * cs) : fmaf(-pt, sn, v * cs);
            if (scaleq) o *= SCv;
            int h = (nt * 16 + lr) >> 3, j = lr & 7;
            dst[((size_t)(b * NH + h) * SEQ + s) * DQKPAD + 64 + j] = __float2bfloat16(o);
        }
    }
    // zero pads [72,96) for all 8 heads of these 128 rows
    for (int u = tid; u < 128 * 96; u += 256) {
        int rw = u / 96, rem = u - rw * 96;
        int h = rem / 12, c = rem - h * 12;
        int row = m0 + rw, b2 = row >> 11, s2 = row & 2047;
        *(unsigned int*)&dst[((size_t)(b2 * NH + h) * SEQ + s2) * DQKPAD + 72 + c * 2] = 0u;
    }
}

// ------- 128x64 bf16 MFMA GEMM body, BK=64, global_load_lds staging + XOR swizzle -------
// modes: 0 bf16->C0 (n0==640: kr-rope -> kv_k); 1 dual->C0/C0f;
// 3 KV-scatter (K direct, V via LDS transpose); 4 Q-scatter scaled (n0==512: q-rope).
static __device__ __forceinline__ void gemm_body(
    int bx, int by,
    const bf16* __restrict__ A, int lda,
    const bf16* __restrict__ BT, int ldb,
    int N, int Kpad, int mode,
    void* __restrict__ C0, int ldc,
    bf16* __restrict__ kv_k, bf16* __restrict__ kv_v,
    const int* __restrict__ flagp, float* __restrict__ C0f,
    bf16* LB)
{
    bf16* Al = LB;
    bf16* Bl = LB + 128 * 64;
    const int tid = threadIdx.x;
    const int m0 = by * 128, n0 = bx * 64;
    const int lane = tid & 63, w = tid >> 6;
    const int g = lane >> 4, lr = lane & 15;
    f32x4 acc[2][4] = {};
    const int r8 = lane >> 3;
    const int xr8 = ((lane & 7) ^ r8) * 8;     // pre-swizzled source column (elems)
    const int swx = (lr & 7) << 4;             // read-side XOR (bytes)

    for (int k0 = 0; k0 < Kpad; k0 += 64) {
        #pragma unroll
        for (int i = 0; i < 4; ++i)
            GL16(&A[(size_t)(m0 + w * 32 + i * 8 + r8) * lda + k0 + xr8],
                 (char*)Al + w * 4096 + i * 1024);
        #pragma unroll
        for (int i = 0; i < 2; ++i)
            GL16(&BT[(size_t)(n0 + w * 16 + i * 8 + r8) * ldb + k0 + xr8],
                 (char*)Bl + w * 2048 + i * 1024);
        __syncthreads();
        #pragma unroll
        for (int ks = 0; ks < 2; ++ks) {
            const int cs = (ks * 64 + g * 16) ^ swx;
            bf16x8 a0 = ld_bf8((const bf16*)((const char*)Al + (w * 32 + lr) * 128 + cs));
            bf16x8 a1 = ld_bf8((const bf16*)((const char*)Al + (w * 32 + 16 + lr) * 128 + cs));
            #pragma unroll
            for (int nt = 0; nt < 4; ++nt) {
                bf16x8 b = ld_bf8((const bf16*)((const char*)Bl + (nt * 16 + lr) * 128 + cs));
                acc[0][nt] = __builtin_amdgcn_mfma_f32_16x16x32_bf16(a0, b, acc[0][nt], 0, 0, 0);
                acc[1][nt] = __builtin_amdgcn_mfma_f32_16x16x32_bf16(a1, b, acc[1][nt], 0, 0, 0);
            }
        }
        __syncthreads();
    }

    if (mode == 0 && n0 == 640) {       // kr-rope block (unscaled) -> k_attn
        rope_epi(acc, kv_k, m0, w, g, lr, tid, false);
        return;
    }
    if (mode == 4 && n0 == DM) {        // qr-rope block (scaled) -> q_attn
        rope_epi(acc, (bf16*)C0, m0, w, g, lr, tid, true);
        return;
    }
    if (mode == 3 && n0 >= DM) {
        // V block: LDS transpose -> coalesced V^T rows
        const int h = (n0 - DM) >> 6;
        const int b = m0 >> 11, s0 = m0 & 2047;
        bf16* T = LB;   // [64][stride 136]
        #pragma unroll
        for (int mt = 0; mt < 2; ++mt)
        #pragma unroll
        for (int nt = 0; nt < 4; ++nt)
        #pragma unroll
        for (int r = 0; r < 4; ++r) {
            int dv = nt * 16 + lr;
            int sl = w * 32 + mt * 16 + g * 4 + r;
            T[dv * 136 + sl] = __float2bfloat16(acc[mt][nt][r]);
        }
        __syncthreads();
        const int row = tid >> 2, coff = (tid & 3) * 32;
        bf16* dst = &kv_v[((size_t)(b * NH + h) * DHD + row) * SEQ + s0 + coff];
        const bf16* srcp = &T[row * 136 + coff];
        #pragma unroll
        for (int q2 = 0; q2 < 4; ++q2)
            *(uint4*)(dst + q2 * 8) = *(const uint4*)(srcp + q2 * 8);
        return;
    }

    const float SCv = 0.11785113019775793f;
    const int f32o = (mode == 1 && flagp) ? *flagp : 0;
    #pragma unroll
    for (int mt = 0; mt < 2; ++mt)
    #pragma unroll
    for (int nt = 0; nt < 4; ++nt)
    #pragma unroll
    for (int r = 0; r < 4; ++r) {
        int gm = m0 + w * 32 + mt * 16 + g * 4 + r;
        int gn = n0 + nt * 16 + lr;
        float v = acc[mt][nt][r];
        if (mode == 0) {
            ((bf16*)C0)[(size_t)gm * ldc + gn] = __float2bfloat16(v);
        } else if (mode == 1) {
            if (f32o) C0f[(size_t)gm * ldc + gn] = v;
            else ((bf16*)C0)[(size_t)gm * ldc + gn] = __float2bfloat16(v);
        } else if (mode == 4) {
            int b = gm >> 11, s = gm & 2047;
            int h = gn >> 6, dh = gn & 63;
            ((bf16*)C0)[((size_t)(b * NH + h) * SEQ + s) * DQKPAD + dh] = __float2bfloat16(v * SCv);
        } else { // mode 3 K block: direct scatter [bh][s][96]
            int b = gm >> 11, s = gm & 2047;
            int h = gn >> 6, dh = gn & 63;
            kv_k[((size_t)(b * NH + h) * SEQ + s) * DQKPAD + dh] = __float2bfloat16(v);
        }
    }
}

__global__ __launch_bounds__(256) void gemm128(
    const bf16* __restrict__ A, int lda,
    const bf16* __restrict__ BT, int ldb,
    int N, int Kpad, int mode,
    void* __restrict__ C0, int ldc,
    bf16* __restrict__ kv_k, bf16* __restrict__ kv_v,
    const int* __restrict__ flagp, float* __restrict__ C0f)
{
    __shared__ __align__(16) bf16 LB[128 * 64 + 64 * 64];   // Al 16KB | Bl 8KB
    gemm_body(blockIdx.x, blockIdx.y, A, lda, BT, ldb, N, Kpad, mode,
              C0, ldc, kv_k, kv_v, flagp, C0f, LB);
}

// ---- merged up-projections: blocks 0..8 = uq (N=576,K=256), 9..24 = ukv (N=1024,K=384) ----
__global__ __launch_bounds__(256) void gemm_dual(
    const bf16* __restrict__ A1, const bf16* __restrict__ BT1, void* __restrict__ C1,
    const bf16* __restrict__ A2, const bf16* __restrict__ BT2,
    bf16* __restrict__ kv_k, bf16* __restrict__ kv_v)
{
    __shared__ __align__(16) bf16 LB[128 * 64 + 64 * 64];
    if (blockIdx.x < 9) {
        gemm_body(blockIdx.x, blockIdx.y, A1, QP, BT1, QP, 576, QP, 4,
                  C1, 0, nullptr, nullptr, nullptr, nullptr, LB);
    } else {
        gemm_body(blockIdx.x - 9, blockIdx.y, A2, 384, BT2, 384, 1024, 384, 3,
                  nullptr, 0, kv_k, kv_v, nullptr, nullptr, LB);
    }
}

// ------- merged layernorms, one wave per row (bf16 y input) -------
__global__ __launch_bounds__(256) void ln_both(
    const bf16* __restrict__ y,
    const bf16* __restrict__ qg, const bf16* __restrict__ qb,
    const bf16* __restrict__ kg, const bf16* __restrict__ kb,
    bf16* __restrict__ cq, bf16* __restrict__ ckv_b, float* __restrict__ ckv_f,
    bf16* __restrict__ ckvp, const int* __restrict__ flagp)
{
    const int w = threadIdx.x >> 6, lane = threadIdx.x & 63;
    const int blk = blockIdx.x;
    if (blk < 1024) {
        const int row = blk * 4 + w;
        const bf16* yr = y + (size_t)row * 704;
        float s = 0.f, ss = 0.f;
        for (int i = lane; i < 256; i += 64) { float v = __bfloat162float(yr[i]); s += v; ss += v * v; }
        #pragma unroll
        for (int m = 1; m < 64; m <<= 1) { s += __shfl_xor(s, m); ss += __shfl_xor(ss, m); }
        float mean = s * (1.f / 256.f);
        float var = ss * (1.f / 256.f) - mean * mean;
        float rstd = rsqrtf(var + 1e-5f);
        for (int i = lane; i < 256; i += 64) {
            float v = (__bfloat162float(yr[i]) - mean) * rstd * __bfloat162float(qg[i]) + __bfloat162float(qb[i]);
            cq[(size_t)row * 256 + i] = __float2bfloat16(v);
        }
    } else {
        const int row = (blk - 1024) * 4 + w;
        const bf16* yr = y + (size_t)row * 704 + 256;
        const int f32o = *flagp;
        float s = 0.f, ss = 0.f;
        for (int i = lane; i < KVP; i += 64) { float v = __bfloat162float(yr[i]); s += v; ss += v * v; }
        #pragma unroll
        for (int m = 1; m < 64; m <<= 1) { s += __shfl_xor(s, m); ss += __shfl_xor(ss, m); }
        float mean = s * (1.f / 341.f);
        float var = ss * (1.f / 341.f) - mean * mean;
        float rstd = rsqrtf(var + 1e-5f);
        for (int i = lane; i < KVP; i += 64) {
            float v = (__bfloat162float(yr[i]) - mean) * rstd * __bfloat162float(kg[i]) + __bfloat162float(kb[i]);
            if (f32o) ckv_f[(size_t)row * KVP + i] = v;
            else ckv_b[(size_t)row * KVP + i] = __float2bfloat16(v);
            ckvp[(size_t)row * 384 + i] = __float2bfloat16(v);
        }
        for (int i = KVP + lane; i < 384; i += 64) ckvp[(size_t)row * 384 + i] = __float2bfloat16(0.f);
    }
}

// ---- causal flash attention: 4-way split-KV + qb-pairing + swapped QK^T
//      + defer-max + T14 async-STAGE + T2 Kl-swizzle + T5 setprio ----
// m/l partials in interleaved [bh][q][4] layout (float4 for combine).
__global__ __launch_bounds__(256) void attn_split3(
    const bf16* __restrict__ qa, const bf16* __restrict__ ka, const bf16* __restrict__ vat,
    bf16* __restrict__ po, float* __restrict__ mlm, float* __restrict__ mll)
{
    __shared__ __align__(16) bf16 Kl[64][128];   // 16 swizzled 8-elem slots (12 used)
    __shared__ __align__(16) bf16 Vt[64][72];
    __shared__ __align__(16) bf16 Pl[4][16][72];
    const int sp = blockIdx.x, pr = blockIdx.y, bh = blockIdx.z;
    const int tid = threadIdx.x, w = tid >> 6, lane = tid & 63;
    const int g = lane >> 4, lr = lane & 15;
    const size_t base = (size_t)bh * SEQ;
    const float L2E = 1.4426950408889634f;
    const bf16* vb = vat + (size_t)bh * DHD * SEQ;

    uint4 kreg0, kreg1, kreg2, vreg0, vreg1;
    const int vd = tid >> 2, vko = (tid & 3) * 16;
    const int kr0 = tid / 12,          ks0 = tid % 12;
    const int kr1 = (tid + 256) / 12,  ks1 = (tid + 256) % 12;
    const int kr2 = (tid + 512) / 12,  ks2 = (tid + 512) % 12;
    const int kx0 = (ks0 ^ (kr0 & 15)) * 8;
    const int kx1 = (ks1 ^ (kr1 & 15)) * 8;
    const int kx2 = (ks2 ^ (kr2 & 15)) * 8;

    #define ISSUE_KV(j0)  do { \
        kreg0 = *(const uint4*)&ka[(base + (j0) + kr0) * DQKPAD + ks0 * 8]; \
        kreg1 = *(const uint4*)&ka[(base + (j0) + kr1) * DQKPAD + ks1 * 8]; \
        kreg2 = *(const uint4*)&ka[(base + (j0) + kr2) * DQKPAD + ks2 * 8]; \
        const bf16* vsrc = &vb[(size_t)vd * SEQ + (j0) + vko]; \
        vreg0 = *(const uint4*)vsrc; vreg1 = *(const uint4*)(vsrc + 8); \
    } while (0)

    for (int half = 0; half < 2; ++half) {
        const int qb = half ? (31 - pr) : pr;
        const int qrow0 = qb * 64 + w * 16;
        const int myq = qrow0 + lr;

        bf16x8 qf[3];
        #pragma unroll
        for (int kc = 0; kc < 3; ++kc)
            qf[kc] = ld_bf8(&qa[(base + myq) * DQKPAD + kc * 32 + g * 8]);

        float m_p = -1e30f, l_p = 0.f;
        f32x4 acc_o[4] = {};
        const int ng = qb + 1;
        const int bs = (ng * sp) >> 2, be = (ng * (sp + 1)) >> 2;

        if (bs < be) ISSUE_KV(bs * 64);

        for (int gi = bs; gi < be; ++gi) {
            const int j0 = gi * 64;
            __syncthreads();
            *(uint4*)&Kl[kr0][kx0] = kreg0;
            *(uint4*)&Kl[kr1][kx1] = kreg1;
            *(uint4*)&Kl[kr2][kx2] = kreg2;
            *(uint4*)&Vt[vd][vko]     = vreg0;
            *(uint4*)&Vt[vd][vko + 8] = vreg1;
            __syncthreads();
            if (gi + 1 < be) ISSUE_KV(j0 + 64);

            f32x4 accs[4] = {};
            __builtin_amdgcn_s_setprio(1);
            #pragma unroll
            for (int kc = 0; kc < 3; ++kc) {
                #pragma unroll
                for (int nt = 0; nt < 4; ++nt) {
                    bf16x8 kf = ld_bf8(&Kl[nt * 16 + lr][((kc * 4 + g) ^ lr) * 8]);
                    accs[nt] = __builtin_amdgcn_mfma_f32_16x16x32_bf16(kf, qf[kc], accs[nt], 0, 0, 0);
                }
            }
            __builtin_amdgcn_s_setprio(0);
            float s_[4][4];
            float mloc = -1e30f;
            if (j0 + 63 > qrow0) {
                #pragma unroll
                for (int nt = 0; nt < 4; ++nt)
                #pragma unroll
                for (int r = 0; r < 4; ++r) {
                    int key = j0 + nt * 16 + g * 4 + r;
                    float sv = accs[nt][r];
                    sv = (key <= myq) ? sv : -1e30f;
                    s_[nt][r] = sv;
                    mloc = fmaxf(mloc, sv);
                }
            } else {
                #pragma unroll
                for (int nt = 0; nt < 4; ++nt)
                #pragma unroll
                for (int r = 0; r < 4; ++r) {
                    float sv = accs[nt][r];
                    s_[nt][r] = sv;
                    mloc = fmaxf(mloc, sv);
                }
            }
            mloc = fmaxf(mloc, __shfl_xor(mloc, 16));
            mloc = fmaxf(mloc, __shfl_xor(mloc, 32));

            if (__all(mloc <= m_p + 8.f)) {
                float rs = 0.f;
                #pragma unroll
                for (int nt = 0; nt < 4; ++nt)
                #pragma unroll
                for (int r = 0; r < 4; ++r) {
                    float p = exp2f((s_[nt][r] - m_p) * L2E);
                    s_[nt][r] = p; rs += p;
                }
                rs += __shfl_xor(rs, 16);
                rs += __shfl_xor(rs, 32);
                l_p += rs;
            } else {
                float mn = fmaxf(m_p, mloc);
                float alpha = exp2f((m_p - mn) * L2E);
                m_p = mn;
                float rs = 0.f;
                #pragma unroll
                for (int nt = 0; nt < 4; ++nt)
                #pragma unroll
                for (int r = 0; r < 4; ++r) {
                    float p = exp2f((s_[nt][r] - mn) * L2E);
                    s_[nt][r] = p; rs += p;
                }
                rs += __shfl_xor(rs, 16);
                rs += __shfl_xor(rs, 32);
                l_p = l_p * alpha + rs;
                float ar[4];
                #pragma unroll
                for (int r = 0; r < 4; ++r) ar[r] = __shfl(alpha, g * 4 + r);
                #pragma unroll
                for (int nv = 0; nv < 4; ++nv)
                #pragma unroll
                for (int r = 0; r < 4; ++r) acc_o[nv][r] *= ar[r];
            }
            #pragma unroll
            for (int nt = 0; nt < 4; ++nt) {
                ushort4 pk;
                pk.x = __builtin_bit_cast(u16, __float2bfloat16(s_[nt][0]));
                pk.y = __builtin_bit_cast(u16, __float2bfloat16(s_[nt][1]));
                pk.z = __builtin_bit_cast(u16, __float2bfloat16(s_[nt][2]));
                pk.w = __builtin_bit_cast(u16, __float2bfloat16(s_[nt][3]));
                *(ushort4*)&Pl[w][lr][nt * 16 + g * 4] = pk;
            }
            bf16x8 pf0 = ld_bf8(&Pl[w][lr][g * 8]);
            bf16x8 pf1 = ld_bf8(&Pl[w][lr][32 + g * 8]);
            __builtin_amdgcn_s_setprio(1);
            #pragma unroll
            for (int nv = 0; nv < 4; ++nv) {
                bf16x8 vf0 = ld_bf8(&Vt[nv * 16 + lr][g * 8]);
                acc_o[nv] = __builtin_amdgcn_mfma_f32_16x16x32_bf16(pf0, vf0, acc_o[nv], 0, 0, 0);
                bf16x8 vf1 = ld_bf8(&Vt[nv * 16 + lr][32 + g * 8]);
                acc_o[nv] = __builtin_amdgcn_mfma_f32_16x16x32_bf16(pf1, vf1, acc_o[nv], 0, 0, 0);
            }
            __builtin_amdgcn_s_setprio(0);
        }

        const size_t pb = (size_t)(bh * NSPLIT + sp) * SEQ;
        #pragma unroll
        for (int r = 0; r < 4; ++r) {
            int qrow = qrow0 + g * 4 + r;
            #pragma unroll
            for (int nv = 0; nv < 4; ++nv)
                po[(pb + qrow) * DHD + nv * 16 + lr] = __float2bfloat16(acc_o[nv][r]);
        }
        if (lane < 16) {
            size_t mi = ((size_t)bh * SEQ + qrow0 + lane) * 4 + sp;
            mlm[mi] = m_p;
            mll[mi] = l_p;
        }
    }
    #undef ISSUE_KV
}

// ---------------- combine split partials -> attn_o [b][s][h*64+d] ----------------
__global__ __launch_bounds__(256) void attn_combine(
    const bf16* __restrict__ po, const float* __restrict__ mlm, const float* __restrict__ mll,
    bf16* __restrict__ ao)
{
    int id = blockIdx.x * 256 + threadIdx.x;   // 16*2048*8 = 262144
    int bh = id >> 14;
    int rem = id & 16383;
    int q = rem >> 3, dc = (rem & 7) * 8;
    const float L2E = 1.4426950408889634f;
    size_t mi = ((size_t)bh * SEQ + q) * 4;
    f32x4 ms = *(const f32x4*)&mlm[mi];
    f32x4 ls = *(const f32x4*)&mll[mi];
    float M = fmaxf(fmaxf(ms[0], ms[1]), fmaxf(ms[2], ms[3]));
    float wsc[NSPLIT]; float L = 0.f;
    #pragma unroll
    for (int s = 0; s < NSPLIT; ++s) { wsc[s] = exp2f((ms[s] - M) * L2E); L += wsc[s] * ls[s]; }
    float o[8] = {};
    #pragma unroll
    for (int s = 0; s < NSPLIT; ++s) {
        if (ls[s] <= 0.f) continue;
        bf16x8 pv = ld_bf8(&po[((size_t)(bh * NSPLIT + s) * SEQ + q) * DHD + dc]);
        #pragma unroll
        for (int j = 0; j < 8; ++j) o[j] += wsc[s] * (float)pv[j];
    }
    float invL = 1.f / L;
    int b = bh >> 3, h = bh & 7;
    __bf16 tmp[8];
    #pragma unroll
    for (int j = 0; j < 8; ++j) tmp[j] = (__bf16)(o[j] * invL);
    *(uint4*)&ao[((size_t)(b * SEQ) + q) * DM + h * DHD + dc] = *(uint4*)tmp;
}

extern "C" void kernel_launch(void* const* d_in, const int* in_sizes, int n_in,
                              void* d_out, int out_size, void* d_ws, size_t ws_size,
                              hipStream_t stream) {
    char* ws = (char*)d_ws;
    bf16* AR      = (bf16*)(ws + 0);              // arena: x | W_o | params
    float* ml_m   = (float*)(ws + 0);             // alias x region (dead after x-gemm), 512KB
    float* ml_l   = (float*)(ws + 1048576);       // 512KB
    bf16* WT      = (bf16*)(ws + 6391296);        // transposed weights (1,802,240 B)
    int*  flagp   = (int*)(ws + 8193536);
    bf16* y       = (bf16*)(ws + 8194048);        // fused x-proj out [4096][704] bf16
    bf16* cq      = (bf16*)(ws + 19728384);       // [4096][256]
    bf16* ckvp    = (bf16*)(ws + 21825536);       // [4096][384]
    bf16* q_attn  = (bf16*)(ws + 26019840);
    bf16* k_attn  = (bf16*)(ws + 32311296);
    bf16* v_attnT = (bf16*)(ws + 38602752);
    bf16* attn_o  = (bf16*)(ws + 42797056);
    bf16* po      = (bf16*)(ws + 50331648);       // 4-split partials, 16,777,216 B

    const bf16* xb  = AR + OFF_X;
    const bf16* W_o = AR + OFF_WO;
    const bf16* qg  = AR + OFF_QG;
    const bf16* qb_ = AR + OFF_QB;
    const bf16* kg  = AR + OFF_KG;
    const bf16* kb  = AR + OFF_KB;

    bf16*  out_b = (bf16*)d_out;
    float* out_f = (float*)d_out;
    bf16*  ckv_b = out_b + (size_t)MROWS * DM;
    float* ckv_f = out_f + (size_t)MROWS * DM;

    dim3 blk(256);
    // 1) prep: flag + convert + weight transposes (8-wide)
    prep<<<dim3((G_TOT + 255) / 256), blk, 0, stream>>>(
        d_in[0], d_in[1], d_in[2], d_in[3], d_in[4], d_in[5],
        d_in[6], d_in[7], d_in[8], d_in[9], d_in[10], d_in[11],
        (u16*)AR, (u16*)WT, flagp);
    // 2) fused x-proj [dq|dkv|kr] N=704, bf16 y (n0==640 block does kr-rope -> k_attn)
    gemm128<<<dim3(11, 32), blk, 0, stream>>>(xb, DM, WT + T_DQ, DM, 704, DM, 0, y, 704, k_attn, nullptr, nullptr, nullptr);
    // 3) merged layernorms (bf16 y in)
    ln_both<<<dim3(2048), blk, 0, stream>>>(y, qg, qb_, kg, kb, cq, ckv_b, ckv_f, ckvp, flagp);
    // 4+5) merged up-projections: uq (q-rope) + ukv (K/V^T scatter)
    gemm_dual<<<dim3(25, 32), blk, 0, stream>>>(cq, WT + T_UQ, q_attn, ckvp, WT + T_UKV, k_attn, v_attnT);
    // 6) attention (4-way split-KV, qb-paired, swapped-softmax, defer-max, T14, T2, T5)
    attn_split3<<<dim3(NSPLIT, 16, 16), blk, 0, stream>>>(q_attn, k_attn, v_attnT, po, ml_m, ml_l);
    // 7) combine (float4 m/l)
    attn_combine<<<dim3(1024), blk, 0, stream>>>(po, ml_m, ml_l, attn_o);
    // 8) output projection -> d_out (dual dtype)
    gemm128<<<dim3(8, 32), blk, 0, stream>>>(attn_o, DM, W_o, DM, DM, DM, 1, out_b, DM, nullptr, nullptr, flagp, out_f);
}